// Round 9
// baseline (250.102 us; speedup 1.0000x reference)
//
#include <hip/hip_runtime.h>
#include <hip/hip_bf16.h>

typedef __hip_bfloat16 bf16_t;
typedef __attribute__((ext_vector_type(8))) short bfrag8;   // 8 bf16 (4 VGPRs)
typedef __attribute__((ext_vector_type(4))) float floatx4;  // MFMA acc

#define DM     1024
#define DI     2048
#define NHD    32
#define HD     64
#define DSTATE 128
#define CONVD  2304
#define NPROJ  4384
#define NPAD   4480
#define MR     4096      // B*L
#define LL     2048
#define EPSF   1e-5f
#define LOG2E  1.44269504088896f

__device__ __forceinline__ void gl_lds16(const void* g, void* l) {
  __builtin_amdgcn_global_load_lds((const __attribute__((address_space(1))) void*)g,
                                   (__attribute__((address_space(3))) void*)l, 16, 0, 0);
}
__device__ __forceinline__ unsigned pack_bf16_rn(float a, float b) {
  unsigned ua = (__float_as_uint(a) + 0x8000u) >> 16;
  unsigned ub = (__float_as_uint(b) + 0x8000u) >> 16;
  return ua | (ub << 16);
}
__device__ __forceinline__ unsigned short bf16u(float a) {
  return (unsigned short)((__float_as_uint(a) + 0x8000u) >> 16);
}
__device__ __forceinline__ float blo(unsigned u){ return __uint_as_float(u << 16); }
__device__ __forceinline__ float bhi(unsigned u){ return __uint_as_float(u & 0xffff0000u); }
__device__ __forceinline__ void unp8(uint4 u, float* v) {
  v[0]=blo(u.x); v[1]=bhi(u.x); v[2]=blo(u.y); v[3]=bhi(u.y);
  v[4]=blo(u.z); v[5]=bhi(u.z); v[6]=blo(u.w); v[7]=bhi(u.w);
}
typedef union { unsigned u[4]; bfrag8 f; } fragu;

// ------------- merged: rmsnorm(x)->ub  +  weights fp32->bf16 (gnorm folded) ----------
#define W1CNT (NPAD * DM / 4)
#define W2CNT (DM * DI / 4)
#define CVTBLK ((W1CNT + W2CNT) / 256)
__global__ void rms_cvt_kernel(const float* __restrict__ x, const float* __restrict__ w,
                               bf16_t* __restrict__ ub,
                               const float* __restrict__ w1, const float* __restrict__ w2,
                               const float* __restrict__ gw,
                               bf16_t* __restrict__ o1, bf16_t* __restrict__ o2) {
  __shared__ float red[4];
  int t = threadIdx.x;
  if (blockIdx.x < MR) {
    int row = blockIdx.x;
    float4 v = ((const float4*)(x + (long)row * DM))[t];
    float ss = v.x*v.x + v.y*v.y + v.z*v.z + v.w*v.w;
#pragma unroll
    for (int off = 32; off > 0; off >>= 1) ss += __shfl_down(ss, off, 64);
    if ((t & 63) == 0) red[t >> 6] = ss;
    __syncthreads();
    float tot = red[0] + red[1] + red[2] + red[3];
    float rs = rsqrtf(tot * (1.f / DM) + EPSF);
    float4 wv = ((const float4*)w)[t];
    bf16_t* o = ub + (long)row * DM + t * 4;
    o[0] = __float2bfloat16(v.x * rs * wv.x);
    o[1] = __float2bfloat16(v.y * rs * wv.y);
    o[2] = __float2bfloat16(v.z * rs * wv.z);
    o[3] = __float2bfloat16(v.w * rs * wv.w);
  } else {
    int i4 = (blockIdx.x - MR) * 256 + t;
    if (i4 < W1CNT) {
      int idx = i4 * 4;
      int row = idx >> 10;
      float4 v = make_float4(0.f, 0.f, 0.f, 0.f);
      if (row < NPROJ) v = *(const float4*)(w1 + idx);
      bf16_t* d = o1 + idx;
      d[0] = __float2bfloat16(v.x); d[1] = __float2bfloat16(v.y);
      d[2] = __float2bfloat16(v.z); d[3] = __float2bfloat16(v.w);
    } else {
      int idx = (i4 - W1CNT) * 4;
      int k = idx & (DI - 1);
      float4 v = *(const float4*)(w2 + idx);
      float4 g = *(const float4*)(gw + k);
      bf16_t* d = o2 + idx;
      d[0] = __float2bfloat16(v.x * g.x); d[1] = __float2bfloat16(v.y * g.y);
      d[2] = __float2bfloat16(v.z * g.z); d[3] = __float2bfloat16(v.w * g.w);
    }
  }
}

// ---------------- out_proj: TM=256 two-half MFMA GEMM + fused rms/residual ----------------
// out[M,DM] = yg[M,DI] @ w2b[DM,DI]^T * rs_row + x. 512 threads: two stacked 128-row
// halves (waves 0-3 / 4-7) sharing one B panel staged by half 0 (proven R3/R6 remainder
// pattern). TM=256 halves B re-reads vs the old 32x16 TN=64 grid (L2-BW-bound: 416MB
// -> 352MB). Grid 256 = 1 block/CU but 8 waves + BW-bound regime (R2 trap was 4 waves
// latency-bound). Fused rms reduction covers the block's 256 rows. XCD 4x8 rect swizzle.
__global__ __launch_bounds__(512) void outproj_kernel(const bf16_t* __restrict__ A,
    const bf16_t* __restrict__ Bw, const float* __restrict__ resid,
    const float* __restrict__ ssqp, float* __restrict__ Cout) {
  __shared__ bf16_t As2[2][128 * 64];
  __shared__ bf16_t Bs[64 * 64];
  __shared__ float rsS[256];
  const int t = threadIdx.x;
  const int hh = t >> 8;                   // M-half 0/1 (waves 0-3 / 4-7)
  const int tl = t & 255;
  const int lane = tl & 63, wv = tl >> 6;
  const int l15 = lane & 15, l4 = lane >> 4;
  const int wm = wv << 5;
  const int b = blockIdx.x;
  const int xcd = b & 7, idx = b >> 3;
  const int bx = (xcd & 3) * 4 + (idx & 3);      // m-tile 0..15
  const int by = (xcd >> 2) * 8 + (idx >> 2);    // n-tile 0..15
  const int tmb = bx << 8;                 // block row base (256 rows)
  const int tm = tmb + hh * 128;
  const int tn = by << 6;

  {   // fused rms reduction for this block's 256 rows (512 thr = 2 thr/row)
    int rr = t >> 1;
    const float4* pp = (const float4*)(ssqp + (long)(tmb + rr) * 32 + (t & 1) * 16);
    float s = 0.f;
#pragma unroll
    for (int q = 0; q < 4; q++) { float4 v = pp[q]; s += v.x + v.y + v.z + v.w; }
    s += __shfl_xor(s, 1, 64);
    if ((t & 1) == 0) rsS[rr] = rsqrtf(s * (1.f / DI) + EPSF);
  }

  floatx4 acc[2][4];
#pragma unroll
  for (int i = 0; i < 2; i++)
#pragma unroll
    for (int j = 0; j < 4; j++) acc[i][j] = (floatx4){0.f, 0.f, 0.f, 0.f};

  const int r = tl >> 3;
  const int c8 = tl & 7;
  const int scol = ((c8 ^ (r & 7)) << 3);
  const bf16_t* Ag = A + (long)(tm + r) * DI + scol;
  const bf16_t* Bg = Bw + (long)(tn + r) * DI + scol;
  const int swz = l15 & 7;
  bf16_t* As = &As2[hh][0];

  for (int k0 = 0; k0 < DI; k0 += 64) {
#pragma unroll
    for (int q = 0; q < 4; q++)
      gl_lds16(Ag + (long)(q * 32) * DI + k0, &As[q * 2048 + tl * 8]);
    if (hh == 0) {
#pragma unroll
      for (int q = 0; q < 2; q++)
        gl_lds16(Bg + (long)(q * 32) * DI + k0, &Bs[q * 2048 + tl * 8]);
    }
    __syncthreads();
#pragma unroll
    for (int kk = 0; kk < 2; kk++) {
      bfrag8 af[2], bfr[4];
      const int ch = ((kk << 2) | l4) ^ swz;
#pragma unroll
      for (int j = 0; j < 4; j++)
        bfr[j] = *(const bfrag8*)&Bs[(j * 16 + l15) * 64 + ch * 8];
#pragma unroll
      for (int i = 0; i < 2; i++)
        af[i] = *(const bfrag8*)&As[(wm + i * 16 + l15) * 64 + ch * 8];
#pragma unroll
      for (int i = 0; i < 2; i++)
#pragma unroll
        for (int j = 0; j < 4; j++)
          acc[i][j] = __builtin_amdgcn_mfma_f32_16x16x32_bf16(af[i], bfr[j], acc[i][j], 0, 0, 0);
    }
    __syncthreads();
  }
#pragma unroll
  for (int i = 0; i < 2; i++)
#pragma unroll
    for (int j = 0; j < 4; j++)
#pragma unroll
      for (int r2 = 0; r2 < 4; r2++) {
        int row = tm + wm + i * 16 + l4 * 4 + r2;
        int col = tn + j * 16 + l15;
        float v = acc[i][j][r2] * rsS[row - tmb] + resid[(long)row * DM + col];
        Cout[(long)row * DM + col] = v;
      }
}

// ---------------- 8-phase 256x256 MFMA GEMM + fused remainder (in_proj) ----------------
// Blocks [0,256): 8-phase 256^2 covers cols [0,4096) — T1 XCD rectangle swizzle +
// T2 LDS XOR-swizzle + T3/T4 8-phase counted-vmcnt + T5 setprio. 512 threads = 8 waves.
// Blocks [256,416): cols [4096,4416) (cols>=4416 are pad, never read) as 160 single
// 128x64 tiles with K SPLIT across the two wave-halves — halves the full-drain serial
// latency chain of the tail. Halves combine via a padded f32 LDS buffer after the loop.
// NOTE (round-5 lesson): counted-vmcnt dbuf here measured 2.5x SLOWER — keep full-drain.
__global__ __launch_bounds__(512, 2) void gemm256_kernel(const bf16_t* __restrict__ A,
    const bf16_t* __restrict__ Bw, bf16_t* __restrict__ Cout) {
  __shared__ bf16_t lds[65536];    // 128 KiB
  const int t = threadIdx.x;

  if (blockIdx.x >= 256) {
    // ---- remainder path: cols [4096,4416), 32 m-tiles x 5 n-tiles, K-split halves ----
    const int idx = blockIdx.x - 256;        // 0..159
    const int mi = idx & 31, ni = idx >> 5;  // ni 0..4
    const int hh = t >> 8;                   // K-half 0/1 (waves 0-3 / 4-7)
    const int tl = t & 255;
    const int lane = tl & 63, wv = tl >> 6;
    const int l15 = lane & 15, l4 = lane >> 4;
    const int wm = wv << 5;
    const int tm = mi * 128;
    const int tn = 4096 + ni * 64;
    bf16_t* As = lds + hh * 12288;           // per half: A 8192 + B 4096 elems (24KB)
    bf16_t* Bs = As + 8192;
    float* Rf = (float*)((char*)lds + 49152); // [128][65] f32 reduce buffer (pad 65)
    floatx4 acc[2][4];
#pragma unroll
    for (int i = 0; i < 2; i++)
#pragma unroll
      for (int j = 0; j < 4; j++) acc[i][j] = (floatx4){0.f, 0.f, 0.f, 0.f};
    const int r = tl >> 3;
    const int c8 = tl & 7;
    const int scol = ((c8 ^ (r & 7)) << 3);
    const int kbase = hh * 512;
    const bf16_t* Ag = A + (long)(tm + r) * DM + kbase + scol;
    const bf16_t* Bg = Bw + (long)(tn + r) * DM + kbase + scol;
    const int swz = l15 & 7;
    for (int k0 = 0; k0 < 512; k0 += 64) {   // 8 iters per half (K-split)
#pragma unroll
      for (int q = 0; q < 4; q++)
        gl_lds16(Ag + (long)(q * 32) * DM + k0, &As[q * 2048 + tl * 8]);
#pragma unroll
      for (int q = 0; q < 2; q++)
        gl_lds16(Bg + (long)(q * 32) * DM + k0, &Bs[q * 2048 + tl * 8]);
      __syncthreads();
#pragma unroll
      for (int kk = 0; kk < 2; kk++) {
        bfrag8 af[2], bfr[4];
        const int ch = ((kk << 2) | l4) ^ swz;
#pragma unroll
        for (int j = 0; j < 4; j++)
          bfr[j] = *(const bfrag8*)&Bs[(j * 16 + l15) * 64 + ch * 8];
#pragma unroll
        for (int i = 0; i < 2; i++)
          af[i] = *(const bfrag8*)&As[(wm + i * 16 + l15) * 64 + ch * 8];
#pragma unroll
        for (int i = 0; i < 2; i++)
#pragma unroll
          for (int j = 0; j < 4; j++)
            acc[i][j] = __builtin_amdgcn_mfma_f32_16x16x32_bf16(af[i], bfr[j], acc[i][j], 0, 0, 0);
      }
      __syncthreads();
    }
    // ---- combine K-halves via LDS, half 0 stores ----
    if (hh == 1) {
#pragma unroll
      for (int i = 0; i < 2; i++)
#pragma unroll
        for (int j = 0; j < 4; j++)
#pragma unroll
          for (int r2 = 0; r2 < 4; r2++)
            Rf[(wm + i * 16 + l4 * 4 + r2) * 65 + j * 16 + l15] = acc[i][j][r2];
    }
    __syncthreads();
    if (hh == 0) {
#pragma unroll
      for (int i = 0; i < 2; i++)
#pragma unroll
        for (int j = 0; j < 4; j++)
#pragma unroll
          for (int r2 = 0; r2 < 4; r2++) {
            int rr = wm + i * 16 + l4 * 4 + r2;
            int cc = j * 16 + l15;
            float v = acc[i][j][r2] + Rf[rr * 65 + cc];
            Cout[(long)(tm + rr) * NPAD + tn + cc] = __float2bfloat16(v);
          }
    }
    return;
  }

  const int lane = t & 63, wv = t >> 6;
  const int wm = wv >> 2, wn = wv & 3;
  const int l15 = lane & 15, l4 = lane >> 4;
  // XCD rectangle swizzle: each XCD owns a 4x8 block rectangle (A 2MB + B 4MB set)
  const int xcd = blockIdx.x & 7, idx = blockIdx.x >> 3;
  const int bx = (xcd & 3) * 4 + (idx & 3);
  const int by = (xcd >> 2) * 8 + (idx >> 2);
  const int tm = bx << 8, tn = by << 8;

  // staging: linear LDS dest + inverse-swizzled global source (involution = read swz)
  const int srow = t >> 3;                          // 0..63
  const int scol = ((t & 7) ^ (srow & 7)) << 3;     // elems
  const bf16_t* Ag = A + (long)(tm + srow) * DM + scol;
  const bf16_t* Bg = Bw + (long)(tn + srow) * DM + scol;
  bf16_t* Asl = lds;
  bf16_t* Bsl = lds + 32768;
  // read-side swizzled chunk offsets (bytes within a 128B row)
  const int swl = (l15 & 7) << 4;
  const int ca0 = (l4 * 16) ^ swl;                  // kk=0
  const int ca1 = (64 + l4 * 16) ^ swl;             // kk=1

  floatx4 acc[8][4];
#pragma unroll
  for (int i = 0; i < 8; i++)
#pragma unroll
    for (int j = 0; j < 4; j++) acc[i][j] = (floatx4){0.f, 0.f, 0.f, 0.f};
  bfrag8 bq[8];

#define STG_A(tt, h) { \
  bf16_t* d_ = Asl + (((tt) & 1) * 2 + (h)) * 8192 + t * 8; \
  gl_lds16(Ag + (long)((h) * 128     ) * DM + (tt) * 64, d_); \
  gl_lds16(Ag + (long)((h) * 128 + 64) * DM + (tt) * 64, d_ + 4096); \
}
#define STG_B(tt, h) { \
  bf16_t* d_ = Bsl + (((tt) & 1) * 2 + (h)) * 8192 + t * 8; \
  gl_lds16(Bg + (long)((h) * 128     ) * DM + (tt) * 64, d_); \
  gl_lds16(Bg + (long)((h) * 128 + 64) * DM + (tt) * 64, d_ + 4096); \
}
#define PH(d, q, STG, WT) { \
  const char* Ah_ = (const char*)(Asl + ((d) * 2 + wm) * 8192); \
  const char* Bh_ = (const char*)(Bsl + ((d) * 2 + (wn >> 1)) * 8192); \
  if ((q) == 0) { \
    _Pragma("unroll") \
    for (int j = 0; j < 4; j++) { \
      int r_ = ((wn & 1) << 6) + j * 16 + l15; \
      bq[j * 2]     = *(const bfrag8*)(Bh_ + r_ * 128 + ca0); \
      bq[j * 2 + 1] = *(const bfrag8*)(Bh_ + r_ * 128 + ca1); \
    } \
  } \
  bfrag8 aq0, aq1, aq2, aq3; \
  { int r_ = (q) * 32 + l15; \
    aq0 = *(const bfrag8*)(Ah_ + r_ * 128 + ca0); \
    aq1 = *(const bfrag8*)(Ah_ + r_ * 128 + ca1); \
    aq2 = *(const bfrag8*)(Ah_ + (r_ + 16) * 128 + ca0); \
    aq3 = *(const bfrag8*)(Ah_ + (r_ + 16) * 128 + ca1); } \
  STG; \
  __builtin_amdgcn_s_barrier(); \
  asm volatile("s_waitcnt lgkmcnt(0)" ::: "memory"); \
  __builtin_amdgcn_s_setprio(1); \
  _Pragma("unroll") \
  for (int j = 0; j < 4; j++) { \
    acc[(q)*2  ][j] = __builtin_amdgcn_mfma_f32_16x16x32_bf16(aq0, bq[j*2],   acc[(q)*2  ][j], 0, 0, 0); \
    acc[(q)*2  ][j] = __builtin_amdgcn_mfma_f32_16x16x32_bf16(aq1, bq[j*2+1], acc[(q)*2  ][j], 0, 0, 0); \
    acc[(q)*2+1][j] = __builtin_amdgcn_mfma_f32_16x16x32_bf16(aq2, bq[j*2],   acc[(q)*2+1][j], 0, 0, 0); \
    acc[(q)*2+1][j] = __builtin_amdgcn_mfma_f32_16x16x32_bf16(aq3, bq[j*2+1], acc[(q)*2+1][j], 0, 0, 0); \
  } \
  __builtin_amdgcn_s_setprio(0); \
  WT; \
  __builtin_amdgcn_s_barrier(); \
}

  // prologue: tile0 (A+B) + B(1); vmcnt(4) leaves B(1) in flight
  STG_A(0, 0); STG_A(0, 1); STG_B(0, 0); STG_B(0, 1);
  STG_B(1, 0); STG_B(1, 1);
  asm volatile("s_waitcnt vmcnt(4)" ::: "memory");
  __builtin_amdgcn_s_barrier();

  for (int it = 0; it < 7; ++it) {
    const int ta = 2 * it, tb = ta + 1;
    PH(0, 0, STG_A(tb, 0), {})
    PH(0, 1, STG_A(tb, 1), {})
    PH(0, 2, STG_B(ta + 2, 0), {})
    PH(0, 3, STG_B(ta + 2, 1), asm volatile("s_waitcnt vmcnt(4)" ::: "memory");)
    PH(1, 0, STG_A(ta + 2, 0), {})
    PH(1, 1, STG_A(ta + 2, 1), {})
    PH(1, 2, STG_B(tb + 2, 0), {})
    PH(1, 3, STG_B(tb + 2, 1), asm volatile("s_waitcnt vmcnt(4)" ::: "memory");)
  }
  { // final iteration: tiles 14, 15 — only A(15) left to stage
    PH(0, 0, STG_A(15, 0), {})
    PH(0, 1, STG_A(15, 1), {})
    PH(0, 2, {}, {})
    PH(0, 3, {}, asm volatile("s_waitcnt vmcnt(0)" ::: "memory");)
    PH(1, 0, {}, {})
    PH(1, 1, {}, {})
    PH(1, 2, {}, {})
    PH(1, 3, {}, {})
  }
#undef PH
#undef STG_A
#undef STG_B

  const long crow = tm + wm * 128;
  const int ccol = tn + wn * 64;
#pragma unroll
  for (int qi = 0; qi < 8; qi++)
#pragma unroll
    for (int j = 0; j < 4; j++)
#pragma unroll
      for (int r2 = 0; r2 < 4; r2++) {
        long row = crow + (qi >> 1) * 32 + (qi & 1) * 16 + l4 * 4 + r2;
        int col = ccol + j * 16 + l15;
        Cout[row * NPAD + col] = __float2bfloat16(acc[qi][j][r2]);
      }
}

// ------- merged: chunk-states MFMA (blocks 0..511) + batched S GEMM (512..575) -------
// SL stored as bf16 (values get packed to bf16 before the P-MFMA in yk4 anyway).
// states path reads xdT and applies the decay scale exp2(ctot - acs[l]) on the fly.
__global__ __launch_bounds__(256) void sst_kernel(const bf16_t* __restrict__ xdT,
    const bf16_t* __restrict__ BmT, bf16_t* __restrict__ states,
    const bf16_t* __restrict__ Cmh, const bf16_t* __restrict__ Bmh,
    bf16_t* __restrict__ SL, const float* __restrict__ acs,
    const float* __restrict__ ctot) {
  __shared__ bf16_t As[128 * 32];
  __shared__ bf16_t Bs[128 * 32];
  const int t = threadIdx.x, lane = t & 63, wv = t >> 6;
  const int l15 = lane & 15, l4 = lane >> 4;
  if (blockIdx.x < 512) {
    // ---- states: pure register MFMA GEMM (no LDS, no barriers) ----
    int blk = blockIdx.x;    // bc*32+h
    int bc = blk >> 5;
    floatx4 acc[2][4];
#pragma unroll
    for (int i = 0; i < 2; i++)
#pragma unroll
      for (int j = 0; j < 4; j++) acc[i][j] = (floatx4){0.f, 0.f, 0.f, 0.f};
    const bf16_t* arow = BmT + (long)bc * 128 * 256;
    const bf16_t* brow = xdT + (long)blk * 64 * 256;
    const float* acsb = acs + (long)blk * 256;
    const float at = ctot[blk];      // log2-scaled chunk total (<= acs[l])
#pragma unroll
    for (int kt = 0; kt < 8; kt++) {
      const int lbase = kt * 32 + l4 * 8;
      float e[8];
      *(float4*)&e[0] = *(const float4*)(acsb + lbase);
      *(float4*)&e[4] = *(const float4*)(acsb + lbase + 4);
#pragma unroll
      for (int q = 0; q < 8; q++) e[q] = exp2f(at - e[q]);
      bfrag8 af[2];
      fragu bfr[4];
#pragma unroll
      for (int i = 0; i < 2; i++)
        af[i] = *(const bfrag8*)(arow + (long)(wv * 32 + i * 16 + l15) * 256 + lbase);
#pragma unroll
      for (int j = 0; j < 4; j++) {
        uint4 u = *(const uint4*)(brow + (long)(j * 16 + l15) * 256 + lbase);
        float v[8];
        unp8(u, v);
#pragma unroll
        for (int q2 = 0; q2 < 4; q2++)
          bfr[j].u[q2] = pack_bf16_rn(v[q2 * 2] * e[q2 * 2], v[q2 * 2 + 1] * e[q2 * 2 + 1]);
      }
#pragma unroll
      for (int i = 0; i < 2; i++)
#pragma unroll
        for (int j = 0; j < 4; j++)
          acc[i][j] = __builtin_amdgcn_mfma_f32_16x16x32_bf16(af[i], bfr[j].f, acc[i][j], 0, 0, 0);
    }
#pragma unroll
    for (int i = 0; i < 2; i++)
#pragma unroll
      for (int j = 0; j < 4; j++) {
        int n_base = wv * 32 + i * 16 + l4 * 4;
        int p = j * 16 + l15;
        unsigned lo = pack_bf16_rn(acc[i][j][0], acc[i][j][1]);
        unsigned hi = pack_bf16_rn(acc[i][j][2], acc[i][j][3]);
        *(uint2*)(states + (long)blk * 8192 + p * 128 + n_base) = make_uint2(lo, hi);
      }
  } else {
    // ---- S GEMM: SL[bc][l][s] = Cm[l].Bm[s] (M=N=256 in 128-tiles, K=128) ----
    int idx = blockIdx.x - 512;         // 0..63
    const int bc = idx >> 2;
    const int tm = ((idx >> 1) & 1) << 7;
    const int tn = (idx & 1) << 7;
    const int wm = (wv >> 1) << 6;
    const int wn = (wv & 1) << 6;
    floatx4 acc[4][4];
#pragma unroll
    for (int i = 0; i < 4; i++)
#pragma unroll
      for (int j = 0; j < 4; j++) acc[i][j] = (floatx4){0.f, 0.f, 0.f, 0.f};
    const int arow = t >> 2;
    const int acol = (t & 3) << 3;
    const bf16_t* Ag = Cmh + (long)bc * 256 * DSTATE + (long)(tm + arow) * DSTATE + acol;
    const bf16_t* Bg = Bmh + (long)bc * 256 * DSTATE + (long)(tn + arow) * DSTATE + acol;
    const long k64 = (long)64 * DSTATE;
    for (int k0 = 0; k0 < DSTATE; k0 += 32) {
      gl_lds16(Ag + k0, &As[t * 8]);
      gl_lds16(Ag + k64 + k0, &As[2048 + t * 8]);
      gl_lds16(Bg + k0, &Bs[t * 8]);
      gl_lds16(Bg + k64 + k0, &Bs[2048 + t * 8]);
      __syncthreads();
      bfrag8 af[4], bfr[4];
#pragma unroll
      for (int i = 0; i < 4; i++)
        af[i] = *(const bfrag8*)&As[(wm + i * 16 + l15) * 32 + l4 * 8];
#pragma unroll
      for (int j = 0; j < 4; j++)
        bfr[j] = *(const bfrag8*)&Bs[(wn + j * 16 + l15) * 32 + l4 * 8];
#pragma unroll
      for (int i = 0; i < 4; i++)
#pragma unroll
        for (int j = 0; j < 4; j++)
          acc[i][j] = __builtin_amdgcn_mfma_f32_16x16x32_bf16(af[i], bfr[j], acc[i][j], 0, 0, 0);
      __syncthreads();
    }
    bf16_t* Cb = SL + (long)bc * 65536;
#pragma unroll
    for (int i = 0; i < 4; i++)
#pragma unroll
      for (int j = 0; j < 4; j++)
#pragma unroll
        for (int r = 0; r < 4; r++)
          Cb[(long)(tm + wm + i * 16 + l4 * 4 + r) * 256 + tn + wn + j * 16 + l15] =
              __float2bfloat16(acc[i][j][r]);
  }
}

// ---------------- vectorized conv4 + bias + silu: 8 channels x 4 rows / thread -------
__global__ __launch_bounds__(256) void conv4_kernel(const bf16_t* __restrict__ zxh,
    const float* __restrict__ cw, const float* __restrict__ cb,
    bf16_t* __restrict__ xhb, bf16_t* __restrict__ Bmh, bf16_t* __restrict__ Cmh) {
  int g = blockIdx.x * 256 + threadIdx.x;    // < 1024*288
  int cg = g % 288;
  int blt = g / 288;
  int c0 = cg * 8;
  long bl0 = (long)blt * 4;
  int l0 = (int)(bl0 & (LL - 1));
  const bf16_t* base = zxh + bl0 * NPAD + DI + c0;
  float rv[7][8];
#pragma unroll
  for (int j = 0; j < 7; j++) {
    int dj = j - 3;
    if (l0 + dj >= 0) {
      uint4 u = *(const uint4*)(base + (long)dj * NPAD);
      unp8(u, rv[j]);
    } else {
#pragma unroll
      for (int q = 0; q < 8; q++) rv[j][q] = 0.f;
    }
  }
  float4 wq[8];
#pragma unroll
  for (int q = 0; q < 8; q++) wq[q] = ((const float4*)cw)[c0 + q];
  float bias[8];
  *(float4*)&bias[0] = *(const float4*)(cb + c0);
  *(float4*)&bias[4] = *(const float4*)(cb + c0 + 4);
#pragma unroll
  for (int i = 0; i < 4; i++) {
    unsigned o[4];
#pragma unroll
    for (int q2 = 0; q2 < 4; q2++) {
      float rr[2];
#pragma unroll
      for (int e = 0; e < 2; e++) {
        int q = q2 * 2 + e;
        float a = bias[q] + wq[q].x * rv[i][q] + wq[q].y * rv[i + 1][q]
                + wq[q].z * rv[i + 2][q] + wq[q].w * rv[i + 3][q];
        rr[e] = a / (1.f + __expf(-a));
      }
      o[q2] = pack_bf16_rn(rr[0], rr[1]);
    }
    uint4 ov = make_uint4(o[0], o[1], o[2], o[3]);
    long bl = bl0 + i;
    if (c0 < DI)               *(uint4*)(xhb + bl * DI + c0) = ov;
    else if (c0 < DI + DSTATE) *(uint4*)(Bmh + bl * DSTATE + (c0 - DI)) = ov;
    else                       *(uint4*)(Cmh + bl * DSTATE + (c0 - DI - DSTATE)) = ov;
  }
}

// ------- fused: softplus(dt)+cumsum (per b,c,h) + transpose xdT; BmT branch ----------
// (xdTe eliminated — its decay scale is applied on the fly in sst's states path.)
__global__ __launch_bounds__(256) void xdt_kernel(const bf16_t* __restrict__ xhb,
    const bf16_t* __restrict__ Bmh, const bf16_t* __restrict__ zxh,
    const float* __restrict__ A_log, const float* __restrict__ dtb,
    float* __restrict__ acs, float* __restrict__ ctot,
    bf16_t* __restrict__ xdT, bf16_t* __restrict__ BmT) {
  __shared__ unsigned short Tb[9216];   // 64x72 (xdt) or 1x 128x72 (bmt)
  __shared__ float acsL[256];
  __shared__ float dtsL[256];
  __shared__ float wsum[4];
  int blk = blockIdx.x;
  int t = threadIdx.x;
  if (blk < 512) {
    int h = blk & 31, bc = blk >> 5;
    {   // ---- fused softplus + log2-scaled cumsum ----
      int lane = t & 63, w = t >> 6;
      float Ah = -__expf(A_log[h]) * LOG2E;
      int gl = bc * 256 + t;
      float vv = __bfloat162float(zxh[(long)gl * NPAD + (NPROJ - 32) + h]) + dtb[h];
      float sp = fmaxf(vv, 0.f) + log1pf(__expf(-fabsf(vv)));
      float a = sp * Ah;
#pragma unroll
      for (int off = 1; off < 64; off <<= 1) {
        float v = __shfl_up(a, off, 64);
        if (lane >= off) a += v;
      }
      if (lane == 63) wsum[w] = a;
      __syncthreads();
      float base = 0.f;
      for (int i = 0; i < 4; i++) base += (i < w) ? wsum[i] : 0.f;
      a += base;
      acsL[t] = a;
      dtsL[t] = sp;
      acs[blk * 256 + t] = a;
      if (t == 255) ctot[blk] = a;
      __syncthreads();
    }
    unsigned short* T1 = Tb;
    int l_loc = t >> 2, pg = t & 3;
    for (int lt = 0; lt < 4; lt++) {
      int ll = lt * 64 + l_loc;
      int gl = bc * 256 + ll;
      float w1 = dtsL[ll];
      const uint4* src = (const uint4*)(xhb + (long)gl * DI + h * HD + pg * 16);
      uint4 u0 = src[0], u1 = src[1];
      float v[16];
      unp8(u0, v); unp8(u1, v + 8);
      __syncthreads();
#pragma unroll
      for (int q = 0; q < 16; q++)
        T1[(pg * 16 + q) * 72 + l_loc] = bf16u(v[q] * w1);
      __syncthreads();
      long orow = ((long)blk * 64 + l_loc) * 256 + lt * 64 + pg * 16;
      *(uint4*)(xdT + orow)     = *(uint4*)&T1[l_loc * 72 + pg * 16];
      *(uint4*)(xdT + orow + 8) = *(uint4*)&T1[l_loc * 72 + pg * 16 + 8];
    }
  } else {
    unsigned short* T = Tb;
    int bc = blk - 512;
    int l_loc = t >> 2, ng = t & 3;
    for (int lt = 0; lt < 4; lt++) {
      int gl = bc * 256 + lt * 64 + l_loc;
      const uint4* src = (const uint4*)(Bmh + (long)gl * DSTATE + ng * 32);
      uint4 u[4];
#pragma unroll
      for (int q = 0; q < 4; q++) u[q] = src[q];
      __syncthreads();
      const unsigned short* us = (const unsigned short*)u;
#pragma unroll
      for (int e = 0; e < 32; e++)
        T[(ng * 32 + e) * 72 + l_loc] = us[e];
      __syncthreads();
      int n = t >> 1, lg2 = t & 1;
      long orow = ((long)bc * 128 + n) * 256 + lt * 64 + lg2 * 32;
#pragma unroll
      for (int q = 0; q < 4; q++)
        *(uint4*)(BmT + orow + q * 8) = *(uint4*)&T[n * 72 + lg2 * 32 + q * 8];
    }
  }
}

// ---------------- inter-chunk scan -> init states (bf16 in/out; ctot log2-scaled) -----
__global__ void scan_kernel(const bf16_t* __restrict__ states, const float* __restrict__ ctot,
                            bf16_t* __restrict__ initsb) {
  int id = blockIdx.x * 256 + threadIdx.x;   // < 2*32*8192
  int pn = id & 8191;
  int bh = id >> 13;
  int b = bh >> 5, h = bh & 31;
  float S = 0.f;
#pragma unroll
  for (int c = 0; c < 8; c++) {
    int blk = (b * 8 + c) * 32 + h;
    initsb[(long)blk * 8192 + pn] = __float2bfloat16(S);
    S = exp2f(ctot[blk]) * S + __bfloat162float(states[(long)blk * 8192 + pn]);
  }
}

// ------- MFMA Y: register A-frags (P computed in-layout), no per-tile barriers -------
// 512 threads: waves 0-3 rows 0-127 (mh=0), waves 4-7 rows 128-255 (mh=1).
// SL is bf16 (halves the ~100MB L2/LLC SL stream; values were bf16-packed anyway).
__global__ __launch_bounds__(512, 4) void yk4_kernel(const bf16_t* __restrict__ SL,
     const bf16_t* __restrict__ Cmh, const bf16_t* __restrict__ xhb,
     const bf16_t* __restrict__ zxh, const float* __restrict__ acs,
     const bf16_t* __restrict__ initsb, const bf16_t* __restrict__ xdT,
     const float* __restrict__ Dp, bf16_t* __restrict__ yg, float* __restrict__ ssqp) {
  int bi = blockIdx.x;                       // XCD-swizzled mapping
  int bc = (bi & 7) * 2 + ((bi >> 3) & 1);
  int h = bi >> 4;
  int ablk = bc * 32 + h;
  int t = threadIdx.x;
  int wv = t >> 6;
  int mh = wv >> 2, wsub = wv & 3;
  int lane = t & 63;
  int l15 = lane & 15, l4 = lane >> 4;

  __shared__ float acsS[256];
  __shared__ __align__(16) char bbuf[49152];   // union: {xds 32KB + ins 16KB} / Yt 33.8KB
  bf16_t* xds = (bf16_t*)bbuf;                 // [64][256] swizzled
  bf16_t* ins = (bf16_t*)(bbuf + 32768);       // [64][128] swizzled
  float* Yt = (float*)bbuf;                    // [128][66]

  {
    const bf16_t* xrow_g = xdT + (long)ablk * 64 * 256;
#pragma unroll
    for (int it = 0; it < 4; it++) {
      int sl = it * 512 + t;
      int p = sl >> 5, s = sl & 31;
      int c = (s & 24) | ((s & 7) ^ (p & 7));
      gl_lds16(xrow_g + p * 256 + c * 8, &xds[sl * 8]);
    }
    const bf16_t* irow_g = initsb + (long)ablk * 8192;
#pragma unroll
    for (int it = 0; it < 2; it++) {
      int sl = it * 512 + t;
      int p = sl >> 4, s = sl & 15;
      int c = (s & 8) | ((s & 7) ^ (p & 7));
      gl_lds16(irow_g + p * 128 + c * 8, &ins[sl * 8]);
    }
  }
  if (t < 256) acsS[t] = acs[ablk * 256 + t];
  __syncthreads();

  const int rowbase = bc * 256;
  const int l0 = mh * 128 + wsub * 32 + l15;
  const int l1 = l0 + 16;
  const float al0 = acsS[l0], al1 = acsS[l1];
  const float eA0 = exp2f(al0), eA1 = exp2f(al1);
  const bf16_t* SL0 = SL + (long)bc * 65536 + (long)l0 * 256;
  const bf16_t* SL1 = SL + (long)bc * 65536 + (long)l1 * 256;

  floatx4 acc[2][4];
#pragma unroll
  for (int i = 0; i < 2; i++)
#pragma unroll
    for (int j = 0; j < 4; j++) acc[i][j] = (floatx4){0.f, 0.f, 0.f, 0.f};

  const int nkd = (mh + 1) * 4;
  for (int kt = 0; kt < nkd; kt++) {           // diagonal tiles, no barriers
    int sbase = kt * 32 + l4 * 8;
    float as[8];
    *(float4*)&as[0] = *(const float4*)&acsS[sbase];
    *(float4*)&as[4] = *(const float4*)&acsS[sbase + 4];
    float sv0[8], sv1[8];
    unp8(*(const uint4*)(SL0 + sbase), sv0);
    unp8(*(const uint4*)(SL1 + sbase), sv1);
    fragu af0, af1;
#pragma unroll
    for (int q2 = 0; q2 < 4; q2++) {
      float p00, p01, p10, p11;
      {
        int s = sbase + q2 * 2;
        float d0 = al0 - as[q2 * 2], d1 = al0 - as[q2 * 2 + 1];
        p00 = (s <= l0) ? sv0[q2 * 2] * exp2f(fminf(d0, 0.f)) : 0.f;
        p01 = (s + 1 <= l0) ? sv0[q2 * 2 + 1] * exp2f(fminf(d1, 0.f)) : 0.f;
        float e0 = al1 - as[q2 * 2], e1 = al1 - as[q2 * 2 + 1];
        p10 = (s <= l1) ? sv1[q2 * 2] * exp2f(fminf(e0, 0.f)) : 0.f;
        p11 = (s + 1 <= l1) ? sv1[q2 * 2 + 1] * exp2f(fminf(e1, 0.f)) : 0.f;
      }
      af0.u[q2] = pack_bf16_rn(p00, p01);
      af1.u[q2] = pack_bf16_rn(p10, p11);
    }
    bfrag8 bfr[4];
    int ch = kt * 4 + l4;
#pragma unroll
    for (int j = 0; j < 4; j++) {
      int p = j * 16 + l15;
      int sw = (ch & 24) | ((ch & 7) ^ (p & 7));
      bfr[j] = *(const bfrag8*)&xds[(p * 32 + sw) * 8];
    }
#pragma unroll
    for (int j = 0; j < 4; j++) {
      acc[0][j] = __builtin_amdgcn_mfma_f32_16x16x32_bf16(af0.f, bfr[j], acc[0][j], 0, 0, 0);
      acc[1][j] = __builtin_amdgcn_mfma_f32_16x16x32_bf16(af1.f, bfr[j], acc[1][j], 0, 0, 0);
    }
  }
#pragma unroll
  for (int kt = 0; kt < 4; kt++) {             // off-diagonal (Y_off) tiles
    int n0 = kt * 32 + l4 * 8;
    uint4 c0 = *(const uint4*)(Cmh + (long)(rowbase + l0) * DSTATE + n0);
    uint4 c1 = *(const uint4*)(Cmh + (long)(rowbase + l1) * DSTATE + n0);
    float cv0[8], cv1[8];
    unp8(c0, cv0); unp8(c1, cv1);
    fragu af0, af1;
#pragma unroll
    for (int q2 = 0; q2 < 4; q2++) {
      af0.u[q2] = pack_bf16_rn(cv0[q2 * 2] * eA0, cv0[q2 * 2 + 1] * eA0);
      af1.u[q2] = pack_bf16_rn(cv1[q2 * 2] * eA1, cv1[q2 * 2 + 1] * eA1);
    }
    bfrag8 bfr[4];
    int ch = kt * 4 + l4;
#pragma unroll
    for (int j = 0; j < 4; j++) {
      int p = j * 16 + l15;
      int sw = (ch & 8) | ((ch & 7) ^ (p & 7));
      bfr[j] = *(const bfrag8*)&ins[(p * 16 + sw) * 8];
    }
#pragma unroll
    for (int j = 0; j < 4; j++) {
      acc[0][j] = __builtin_amdgcn_mfma_f32_16x16x32_bf16(af0.f, bfr[j], acc[0][j], 0, 0, 0);
      acc[1][j] = __builtin_amdgcn_mfma_f32_16x16x32_bf16(af1.f, bfr[j], acc[1][j], 0, 0, 0);
    }
  }
  // ---- two-pass epilogue through Yt (union over xds/ins) ----
  float Dh = Dp[h];
#pragma unroll
  for (int pass = 0; pass < 2; pass++) {
    __syncthreads();
    if (mh == pass) {
#pragma unroll
      for (int i = 0; i < 2; i++)
#pragma unroll
        for (int j = 0; j < 4; j++)
#pragma unroll
          for (int r = 0; r < 4; r++)
            Yt[(wsub * 32 + i * 16 + l4 * 4 + r) * 66 + j * 16 + l15] = acc[i][j][r];
    }
    __syncthreads();
    {
      int row_l = t >> 2;
      int chc = (t & 3) * 16;
      long rowg = rowbase + pass * 128 + row_l;
      float ss = 0.f;
#pragma unroll
      for (int it = 0; it < 2; it++) {
        int c = chc + it * 8;
        float4 y0 = *(const float4*)&Yt[row_l * 66 + c];
        float4 y1 = *(const float4*)&Yt[row_l * 66 + c + 4];
        uint4 ux = *(const uint4*)(xhb + rowg * DI + h * HD + c);
        uint4 uz = *(const uint4*)(zxh + rowg * NPAD + h * HD + c);
        float xv[8], zv[8];
        unp8(ux, xv); unp8(uz, zv);
        float yv[8] = {y0.x, y0.y, y0.z, y0.w, y1.x, y1.y, y1.z, y1.w};
        unsigned o[4];
#pragma unroll
        for (int q = 0; q < 4; q++) {
          float v0 = (yv[q * 2 + 0] + Dh * xv[q * 2 + 0]) *
                     (zv[q * 2 + 0] / (1.f + __expf(-zv[q * 2 + 0])));
          float v1 = (yv[q * 2 + 1] + Dh * xv[q * 2 + 1]) *
                     (zv[q * 2 + 1] / (1.f + __expf(-zv[q * 2 + 1])));
          ss += v0 * v0 + v1 * v1;
          o[q] = pack_bf16_rn(v0, v1);
        }
        *(uint4*)(yg + rowg * DI + h * HD + c) = make_uint4(o[0], o[1], o[2], o[3]);
      }
      ss += __shfl_xor(ss, 1, 64);
      ss += __shfl_xor(ss, 2, 64);
      if ((t & 3) == 0) ssqp[rowg * 32 + h] = ss;
    }
  }
}

extern "C" void kernel_launch(void* const* d_in, const int* in_sizes, int n_in,
                              void* d_out, int out_size, void* d_ws, size_t ws_size,
                              hipStream_t stream) {
  const float* x    = (const float*)d_in[0];
  const float* nw   = (const float*)d_in[1];
  const float* w1   = (const float*)d_in[2];
  const float* cw   = (const float*)d_in[3];
  const float* cb   = (const float*)d_in[4];
  const float* dtb  = (const float*)d_in[5];
  const float* alog = (const float*)d_in[6];
  const float* Dp   = (const float*)d_in[7];
  const float* gw   = (const float*)d_in[8];
  const float* w2   = (const float*)d_in[9];
  float* out = (float*)d_out;

  char* ws = (char*)d_ws;
  size_t off = 0;
  auto alloc = [&](size_t bytes) -> void* {
    void* p = ws + off;
    off += (bytes + 255) & ~(size_t)255;
    return p;
  };
  bf16_t* ub     = (bf16_t*)alloc((size_t)MR * DM * 2);
  bf16_t* w1b    = (bf16_t*)alloc((size_t)NPAD * DM * 2);
  bf16_t* w2b    = (bf16_t*)alloc((size_t)DM * DI * 2);
  bf16_t* zxh    = (bf16_t*)alloc((size_t)MR * NPAD * 2);
  bf16_t* xhb    = (bf16_t*)alloc((size_t)MR * DI * 2);
  bf16_t* Bmh    = (bf16_t*)alloc((size_t)MR * DSTATE * 2);
  bf16_t* Cmh    = (bf16_t*)alloc((size_t)MR * DSTATE * 2);
  bf16_t* SL     = (bf16_t*)alloc((size_t)16 * 256 * 256 * 2);
  float* acs     = (float*)alloc((size_t)512 * 256 * 4);
  float* ctot    = (float*)alloc((size_t)512 * 4);
  bf16_t* states = (bf16_t*)alloc((size_t)512 * 8192 * 2);
  bf16_t* initsb = (bf16_t*)alloc((size_t)512 * 8192 * 2);
  bf16_t* xdT    = (bf16_t*)alloc((size_t)512 * 64 * 256 * 2);
  bf16_t* BmT    = (bf16_t*)alloc((size_t)16 * 128 * 256 * 2);
  bf16_t* yg     = (bf16_t*)alloc((size_t)MR * DI * 2);
  float* ssqp    = (float*)alloc((size_t)MR * NHD * 4);
  if (off > ws_size) return;

  rms_cvt_kernel<<<MR + CVTBLK, 256, 0, stream>>>(x, nw, ub, w1, w2, gw, w1b, w2b);
  // in_proj: single launch — 256 main (8-phase 256^2, cols [0,4096)) + 160 K-split
  // remainder blocks (cols [4096,4416); >=4416 is never-read pad).
  gemm256_kernel<<<416, 512, 0, stream>>>(ub, w1b, zxh);
  conv4_kernel<<<(1024 * 288) / 256, 256, 0, stream>>>(zxh, cw, cb, xhb, Bmh, Cmh);
  xdt_kernel<<<528, 256, 0, stream>>>(xhb, Bmh, zxh, alog, dtb, acs, ctot, xdT, BmT);
  sst_kernel<<<576, 256, 0, stream>>>(xdT, BmT, states, Cmh, Bmh, SL, acs, ctot);
  scan_kernel<<<(2 * 32 * 8192) / 256, 256, 0, stream>>>(states, ctot, initsb);
  yk4_kernel<<<512, 512, 0, stream>>>(SL, Cmh, xhb, zxh, acs, initsb, xdT, Dp, yg, ssqp);
  // out_proj: TM=256 two-half structure (halves B re-reads; L2-BW-bound regime)
  outproj_kernel<<<256, 512, 0, stream>>>(yg, w2b, x, ssqp, out);
}

// Round 10
// 246.052 us; speedup vs baseline: 1.0165x; 1.0165x over previous
//
#include <hip/hip_runtime.h>
#include <hip/hip_bf16.h>

typedef __hip_bfloat16 bf16_t;
typedef __attribute__((ext_vector_type(8))) short bfrag8;   // 8 bf16 (4 VGPRs)
typedef __attribute__((ext_vector_type(4))) float floatx4;  // MFMA acc

#define DM     1024
#define DI     2048
#define NHD    32
#define HD     64
#define DSTATE 128
#define CONVD  2304
#define NPROJ  4384
#define NPAD   4480
#define MR     4096      // B*L
#define LL     2048
#define EPSF   1e-5f
#define LOG2E  1.44269504088896f

__device__ __forceinline__ void gl_lds16(const void* g, void* l) {
  __builtin_amdgcn_global_load_lds((const __attribute__((address_space(1))) void*)g,
                                   (__attribute__((address_space(3))) void*)l, 16, 0, 0);
}
__device__ __forceinline__ unsigned pack_bf16_rn(float a, float b) {
  unsigned ua = (__float_as_uint(a) + 0x8000u) >> 16;
  unsigned ub = (__float_as_uint(b) + 0x8000u) >> 16;
  return ua | (ub << 16);
}
__device__ __forceinline__ unsigned short bf16u(float a) {
  return (unsigned short)((__float_as_uint(a) + 0x8000u) >> 16);
}
__device__ __forceinline__ float blo(unsigned u){ return __uint_as_float(u << 16); }
__device__ __forceinline__ float bhi(unsigned u){ return __uint_as_float(u & 0xffff0000u); }
__device__ __forceinline__ void unp8(uint4 u, float* v) {
  v[0]=blo(u.x); v[1]=bhi(u.x); v[2]=blo(u.y); v[3]=bhi(u.y);
  v[4]=blo(u.z); v[5]=bhi(u.z); v[6]=blo(u.w); v[7]=bhi(u.w);
}
typedef union { unsigned u[4]; bfrag8 f; } fragu;

// ------------- merged: rmsnorm(x)->ub  +  weights fp32->bf16 (gnorm folded) ----------
#define W1CNT (NPAD * DM / 4)
#define W2CNT (DM * DI / 4)
#define CVTBLK ((W1CNT + W2CNT) / 256)
__global__ void rms_cvt_kernel(const float* __restrict__ x, const float* __restrict__ w,
                               bf16_t* __restrict__ ub,
                               const float* __restrict__ w1, const float* __restrict__ w2,
                               const float* __restrict__ gw,
                               bf16_t* __restrict__ o1, bf16_t* __restrict__ o2) {
  __shared__ float red[4];
  int t = threadIdx.x;
  if (blockIdx.x < MR) {
    int row = blockIdx.x;
    float4 v = ((const float4*)(x + (long)row * DM))[t];
    float ss = v.x*v.x + v.y*v.y + v.z*v.z + v.w*v.w;
#pragma unroll
    for (int off = 32; off > 0; off >>= 1) ss += __shfl_down(ss, off, 64);
    if ((t & 63) == 0) red[t >> 6] = ss;
    __syncthreads();
    float tot = red[0] + red[1] + red[2] + red[3];
    float rs = rsqrtf(tot * (1.f / DM) + EPSF);
    float4 wv = ((const float4*)w)[t];
    bf16_t* o = ub + (long)row * DM + t * 4;
    o[0] = __float2bfloat16(v.x * rs * wv.x);
    o[1] = __float2bfloat16(v.y * rs * wv.y);
    o[2] = __float2bfloat16(v.z * rs * wv.z);
    o[3] = __float2bfloat16(v.w * rs * wv.w);
  } else {
    int i4 = (blockIdx.x - MR) * 256 + t;
    if (i4 < W1CNT) {
      int idx = i4 * 4;
      int row = idx >> 10;
      float4 v = make_float4(0.f, 0.f, 0.f, 0.f);
      if (row < NPROJ) v = *(const float4*)(w1 + idx);
      bf16_t* d = o1 + idx;
      d[0] = __float2bfloat16(v.x); d[1] = __float2bfloat16(v.y);
      d[2] = __float2bfloat16(v.z); d[3] = __float2bfloat16(v.w);
    } else {
      int idx = (i4 - W1CNT) * 4;
      int k = idx & (DI - 1);
      float4 v = *(const float4*)(w2 + idx);
      float4 g = *(const float4*)(gw + k);
      bf16_t* d = o2 + idx;
      d[0] = __float2bfloat16(v.x * g.x); d[1] = __float2bfloat16(v.y * g.y);
      d[2] = __float2bfloat16(v.z * g.z); d[3] = __float2bfloat16(v.w * g.w);
    }
  }
}

// ---------------- BK=64 swizzled MFMA GEMM: C[M,N] = A[M,K] @ B[N,K]^T ----------------
// DO_RES: fused per-row rms (reduces ssqp partials in-block) + residual add, plus
// bijective 8x8 XCD rectangle swizzle (grid must be 32x16 when DO_RES).
// HARD RULE (R2 + R9 lessons): this 2-barrier structure needs >= 2 blocks/CU.
// Both 1-block/CU variants (TN=128 grid 32x8; TM=256 grid 256) regressed —
// exposed full-drain latency outweighs any L2-traffic saving. TN=64 32x16 only.
template<int TN, bool DO_RES, bool OUT_BF16>
__global__ __launch_bounds__(256) void gemm64_kernel(const bf16_t* __restrict__ A,
    const bf16_t* __restrict__ Bw, const float* __restrict__ resid,
    const float* __restrict__ ssqp, void* __restrict__ Cout, int N, int K) {
  __shared__ bf16_t As[128 * 64];
  __shared__ bf16_t Bs[TN * 64];
  __shared__ float rsS[128];
  const int tid = threadIdx.x;
  const int lane = tid & 63;
  const int wv = tid >> 6;
  const int l15 = lane & 15;
  const int l4 = lane >> 4;
  constexpr int MF = (TN == 128) ? 4 : 2;
  const int wm = (TN == 128) ? ((wv >> 1) << 6) : (wv << 5);
  const int wn = (TN == 128) ? ((wv & 1) << 6) : 0;
  int tm, tn;
  if (DO_RES) {   // XCD rectangle swizzle (512 blocks = 8 XCD x 8x8 rect)
    const int flat = blockIdx.y * gridDim.x + blockIdx.x;
    const int xcd = flat & 7, ridx = flat >> 3;
    tm = ((xcd & 3) * 8 + (ridx & 7)) << 7;
    tn = ((xcd >> 2) * 8 + (ridx >> 3)) * TN;
  } else {
    tm = blockIdx.x << 7;
    tn = blockIdx.y * TN;
  }

  if (DO_RES) {   // fused rms reduction for this block's 128 rows
    int rr = tid >> 1;
    const float4* pp = (const float4*)(ssqp + (long)(tm + rr) * 32 + (tid & 1) * 16);
    float s = 0.f;
#pragma unroll
    for (int q = 0; q < 4; q++) { float4 v = pp[q]; s += v.x + v.y + v.z + v.w; }
    s += __shfl_xor(s, 1, 64);
    if ((tid & 1) == 0) rsS[rr] = rsqrtf(s * (1.f / DI) + EPSF);
  }

  floatx4 acc[MF][4];
#pragma unroll
  for (int i = 0; i < MF; i++)
#pragma unroll
    for (int j = 0; j < 4; j++) acc[i][j] = (floatx4){0.f, 0.f, 0.f, 0.f};

  const int r = tid >> 3;
  const int c8 = tid & 7;
  const int scol = ((c8 ^ (r & 7)) << 3);
  const bf16_t* Ag = A + (long)(tm + r) * K + scol;
  const bf16_t* Bg = Bw + (long)(tn + r) * K + scol;
  const int swz = l15 & 7;

  for (int k0 = 0; k0 < K; k0 += 64) {
#pragma unroll
    for (int q = 0; q < 4; q++)
      gl_lds16(Ag + (long)(q * 32) * K + k0, &As[q * 2048 + tid * 8]);
#pragma unroll
    for (int q = 0; q < TN / 32; q++)
      gl_lds16(Bg + (long)(q * 32) * K + k0, &Bs[q * 2048 + tid * 8]);
    __syncthreads();
#pragma unroll
    for (int kk = 0; kk < 2; kk++) {
      bfrag8 af[MF], bfr[4];
      const int ch = ((kk << 2) | l4) ^ swz;
#pragma unroll
      for (int j = 0; j < 4; j++)
        bfr[j] = *(const bfrag8*)&Bs[(wn + j * 16 + l15) * 64 + ch * 8];
#pragma unroll
      for (int i = 0; i < MF; i++)
        af[i] = *(const bfrag8*)&As[(wm + i * 16 + l15) * 64 + ch * 8];
#pragma unroll
      for (int i = 0; i < MF; i++)
#pragma unroll
        for (int j = 0; j < 4; j++)
          acc[i][j] = __builtin_amdgcn_mfma_f32_16x16x32_bf16(af[i], bfr[j], acc[i][j], 0, 0, 0);
    }
    __syncthreads();
  }
#pragma unroll
  for (int i = 0; i < MF; i++)
#pragma unroll
    for (int j = 0; j < 4; j++)
#pragma unroll
      for (int r2 = 0; r2 < 4; r2++) {
        int row = tm + wm + i * 16 + l4 * 4 + r2;
        int col = tn + wn + j * 16 + l15;
        float v = acc[i][j][r2];
        if (OUT_BF16) {
          ((bf16_t*)Cout)[(long)row * N + col] = __float2bfloat16(v);
        } else {
          if (DO_RES) v = v * rsS[row - tm] + resid[(long)row * N + col];
          ((float*)Cout)[(long)row * N + col] = v;
        }
      }
}

// ---------------- 8-phase 256x256 MFMA GEMM + fused remainder (in_proj) ----------------
// Blocks [0,256): 8-phase 256^2 covers cols [0,4096) — T1 XCD rectangle swizzle +
// T2 LDS XOR-swizzle + T3/T4 8-phase counted-vmcnt + T5 setprio. 512 threads = 8 waves.
// Blocks [256,416): cols [4096,4416) (cols>=4416 are pad, never read) as 160 single
// 128x64 tiles with K SPLIT across the two wave-halves — halves the full-drain serial
// latency chain of the tail. Halves combine via a padded f32 LDS buffer after the loop.
// NOTE (round-5 lesson): counted-vmcnt dbuf here measured 2.5x SLOWER — keep full-drain.
__global__ __launch_bounds__(512, 2) void gemm256_kernel(const bf16_t* __restrict__ A,
    const bf16_t* __restrict__ Bw, bf16_t* __restrict__ Cout) {
  __shared__ bf16_t lds[65536];    // 128 KiB
  const int t = threadIdx.x;

  if (blockIdx.x >= 256) {
    // ---- remainder path: cols [4096,4416), 32 m-tiles x 5 n-tiles, K-split halves ----
    const int idx = blockIdx.x - 256;        // 0..159
    const int mi = idx & 31, ni = idx >> 5;  // ni 0..4
    const int hh = t >> 8;                   // K-half 0/1 (waves 0-3 / 4-7)
    const int tl = t & 255;
    const int lane = tl & 63, wv = tl >> 6;
    const int l15 = lane & 15, l4 = lane >> 4;
    const int wm = wv << 5;
    const int tm = mi * 128;
    const int tn = 4096 + ni * 64;
    bf16_t* As = lds + hh * 12288;           // per half: A 8192 + B 4096 elems (24KB)
    bf16_t* Bs = As + 8192;
    float* Rf = (float*)((char*)lds + 49152); // [128][65] f32 reduce buffer (pad 65)
    floatx4 acc[2][4];
#pragma unroll
    for (int i = 0; i < 2; i++)
#pragma unroll
      for (int j = 0; j < 4; j++) acc[i][j] = (floatx4){0.f, 0.f, 0.f, 0.f};
    const int r = tl >> 3;
    const int c8 = tl & 7;
    const int scol = ((c8 ^ (r & 7)) << 3);
    const int kbase = hh * 512;
    const bf16_t* Ag = A + (long)(tm + r) * DM + kbase + scol;
    const bf16_t* Bg = Bw + (long)(tn + r) * DM + kbase + scol;
    const int swz = l15 & 7;
    for (int k0 = 0; k0 < 512; k0 += 64) {   // 8 iters per half (K-split)
#pragma unroll
      for (int q = 0; q < 4; q++)
        gl_lds16(Ag + (long)(q * 32) * DM + k0, &As[q * 2048 + tl * 8]);
#pragma unroll
      for (int q = 0; q < 2; q++)
        gl_lds16(Bg + (long)(q * 32) * DM + k0, &Bs[q * 2048 + tl * 8]);
      __syncthreads();
#pragma unroll
      for (int kk = 0; kk < 2; kk++) {
        bfrag8 af[2], bfr[4];
        const int ch = ((kk << 2) | l4) ^ swz;
#pragma unroll
        for (int j = 0; j < 4; j++)
          bfr[j] = *(const bfrag8*)&Bs[(j * 16 + l15) * 64 + ch * 8];
#pragma unroll
        for (int i = 0; i < 2; i++)
          af[i] = *(const bfrag8*)&As[(wm + i * 16 + l15) * 64 + ch * 8];
#pragma unroll
        for (int i = 0; i < 2; i++)
#pragma unroll
          for (int j = 0; j < 4; j++)
            acc[i][j] = __builtin_amdgcn_mfma_f32_16x16x32_bf16(af[i], bfr[j], acc[i][j], 0, 0, 0);
      }
      __syncthreads();
    }
    // ---- combine K-halves via LDS, half 0 stores ----
    if (hh == 1) {
#pragma unroll
      for (int i = 0; i < 2; i++)
#pragma unroll
        for (int j = 0; j < 4; j++)
#pragma unroll
          for (int r2 = 0; r2 < 4; r2++)
            Rf[(wm + i * 16 + l4 * 4 + r2) * 65 + j * 16 + l15] = acc[i][j][r2];
    }
    __syncthreads();
    if (hh == 0) {
#pragma unroll
      for (int i = 0; i < 2; i++)
#pragma unroll
        for (int j = 0; j < 4; j++)
#pragma unroll
          for (int r2 = 0; r2 < 4; r2++) {
            int rr = wm + i * 16 + l4 * 4 + r2;
            int cc = j * 16 + l15;
            float v = acc[i][j][r2] + Rf[rr * 65 + cc];
            Cout[(long)(tm + rr) * NPAD + tn + cc] = __float2bfloat16(v);
          }
    }
    return;
  }

  const int lane = t & 63, wv = t >> 6;
  const int wm = wv >> 2, wn = wv & 3;
  const int l15 = lane & 15, l4 = lane >> 4;
  // XCD rectangle swizzle: each XCD owns a 4x8 block rectangle (A 2MB + B 4MB set)
  const int xcd = blockIdx.x & 7, idx = blockIdx.x >> 3;
  const int bx = (xcd & 3) * 4 + (idx & 3);
  const int by = (xcd >> 2) * 8 + (idx >> 2);
  const int tm = bx << 8, tn = by << 8;

  // staging: linear LDS dest + inverse-swizzled global source (involution = read swz)
  const int srow = t >> 3;                          // 0..63
  const int scol = ((t & 7) ^ (srow & 7)) << 3;     // elems
  const bf16_t* Ag = A + (long)(tm + srow) * DM + scol;
  const bf16_t* Bg = Bw + (long)(tn + srow) * DM + scol;
  bf16_t* Asl = lds;
  bf16_t* Bsl = lds + 32768;
  // read-side swizzled chunk offsets (bytes within a 128B row)
  const int swl = (l15 & 7) << 4;
  const int ca0 = (l4 * 16) ^ swl;                  // kk=0
  const int ca1 = (64 + l4 * 16) ^ swl;             // kk=1

  floatx4 acc[8][4];
#pragma unroll
  for (int i = 0; i < 8; i++)
#pragma unroll
    for (int j = 0; j < 4; j++) acc[i][j] = (floatx4){0.f, 0.f, 0.f, 0.f};
  bfrag8 bq[8];

#define STG_A(tt, h) { \
  bf16_t* d_ = Asl + (((tt) & 1) * 2 + (h)) * 8192 + t * 8; \
  gl_lds16(Ag + (long)((h) * 128     ) * DM + (tt) * 64, d_); \
  gl_lds16(Ag + (long)((h) * 128 + 64) * DM + (tt) * 64, d_ + 4096); \
}
#define STG_B(tt, h) { \
  bf16_t* d_ = Bsl + (((tt) & 1) * 2 + (h)) * 8192 + t * 8; \
  gl_lds16(Bg + (long)((h) * 128     ) * DM + (tt) * 64, d_); \
  gl_lds16(Bg + (long)((h) * 128 + 64) * DM + (tt) * 64, d_ + 4096); \
}
#define PH(d, q, STG, WT) { \
  const char* Ah_ = (const char*)(Asl + ((d) * 2 + wm) * 8192); \
  const char* Bh_ = (const char*)(Bsl + ((d) * 2 + (wn >> 1)) * 8192); \
  if ((q) == 0) { \
    _Pragma("unroll") \
    for (int j = 0; j < 4; j++) { \
      int r_ = ((wn & 1) << 6) + j * 16 + l15; \
      bq[j * 2]     = *(const bfrag8*)(Bh_ + r_ * 128 + ca0); \
      bq[j * 2 + 1] = *(const bfrag8*)(Bh_ + r_ * 128 + ca1); \
    } \
  } \
  bfrag8 aq0, aq1, aq2, aq3; \
  { int r_ = (q) * 32 + l15; \
    aq0 = *(const bfrag8*)(Ah_ + r_ * 128 + ca0); \
    aq1 = *(const bfrag8*)(Ah_ + r_ * 128 + ca1); \
    aq2 = *(const bfrag8*)(Ah_ + (r_ + 16) * 128 + ca0); \
    aq3 = *(const bfrag8*)(Ah_ + (r_ + 16) * 128 + ca1); } \
  STG; \
  __builtin_amdgcn_s_barrier(); \
  asm volatile("s_waitcnt lgkmcnt(0)" ::: "memory"); \
  __builtin_amdgcn_s_setprio(1); \
  _Pragma("unroll") \
  for (int j = 0; j < 4; j++) { \
    acc[(q)*2  ][j] = __builtin_amdgcn_mfma_f32_16x16x32_bf16(aq0, bq[j*2],   acc[(q)*2  ][j], 0, 0, 0); \
    acc[(q)*2  ][j] = __builtin_amdgcn_mfma_f32_16x16x32_bf16(aq1, bq[j*2+1], acc[(q)*2  ][j], 0, 0, 0); \
    acc[(q)*2+1][j] = __builtin_amdgcn_mfma_f32_16x16x32_bf16(aq2, bq[j*2],   acc[(q)*2+1][j], 0, 0, 0); \
    acc[(q)*2+1][j] = __builtin_amdgcn_mfma_f32_16x16x32_bf16(aq3, bq[j*2+1], acc[(q)*2+1][j], 0, 0, 0); \
  } \
  __builtin_amdgcn_s_setprio(0); \
  WT; \
  __builtin_amdgcn_s_barrier(); \
}

  // prologue: tile0 (A+B) + B(1); vmcnt(4) leaves B(1) in flight
  STG_A(0, 0); STG_A(0, 1); STG_B(0, 0); STG_B(0, 1);
  STG_B(1, 0); STG_B(1, 1);
  asm volatile("s_waitcnt vmcnt(4)" ::: "memory");
  __builtin_amdgcn_s_barrier();

  for (int it = 0; it < 7; ++it) {
    const int ta = 2 * it, tb = ta + 1;
    PH(0, 0, STG_A(tb, 0), {})
    PH(0, 1, STG_A(tb, 1), {})
    PH(0, 2, STG_B(ta + 2, 0), {})
    PH(0, 3, STG_B(ta + 2, 1), asm volatile("s_waitcnt vmcnt(4)" ::: "memory");)
    PH(1, 0, STG_A(ta + 2, 0), {})
    PH(1, 1, STG_A(ta + 2, 1), {})
    PH(1, 2, STG_B(tb + 2, 0), {})
    PH(1, 3, STG_B(tb + 2, 1), asm volatile("s_waitcnt vmcnt(4)" ::: "memory");)
  }
  { // final iteration: tiles 14, 15 — only A(15) left to stage
    PH(0, 0, STG_A(15, 0), {})
    PH(0, 1, STG_A(15, 1), {})
    PH(0, 2, {}, {})
    PH(0, 3, {}, asm volatile("s_waitcnt vmcnt(0)" ::: "memory");)
    PH(1, 0, {}, {})
    PH(1, 1, {}, {})
    PH(1, 2, {}, {})
    PH(1, 3, {}, {})
  }
#undef PH
#undef STG_A
#undef STG_B

  const long crow = tm + wm * 128;
  const int ccol = tn + wn * 64;
#pragma unroll
  for (int qi = 0; qi < 8; qi++)
#pragma unroll
    for (int j = 0; j < 4; j++)
#pragma unroll
      for (int r2 = 0; r2 < 4; r2++) {
        long row = crow + (qi >> 1) * 32 + (qi & 1) * 16 + l4 * 4 + r2;
        int col = ccol + j * 16 + l15;
        Cout[row * NPAD + col] = __float2bfloat16(acc[qi][j][r2]);
      }
}

// ------- merged: chunk-states MFMA (blocks 0..511) + batched S GEMM (512..575) -------
// SL stored as bf16 (values get packed to bf16 before the P-MFMA in yk4 anyway).
// states path reads xdT and applies the decay scale exp2(ctot - acs[l]) on the fly.
__global__ __launch_bounds__(256) void sst_kernel(const bf16_t* __restrict__ xdT,
    const bf16_t* __restrict__ BmT, bf16_t* __restrict__ states,
    const bf16_t* __restrict__ Cmh, const bf16_t* __restrict__ Bmh,
    bf16_t* __restrict__ SL, const float* __restrict__ acs,
    const float* __restrict__ ctot) {
  __shared__ bf16_t As[128 * 32];
  __shared__ bf16_t Bs[128 * 32];
  const int t = threadIdx.x, lane = t & 63, wv = t >> 6;
  const int l15 = lane & 15, l4 = lane >> 4;
  if (blockIdx.x < 512) {
    // ---- states: pure register MFMA GEMM (no LDS, no barriers) ----
    int blk = blockIdx.x;    // bc*32+h
    int bc = blk >> 5;
    floatx4 acc[2][4];
#pragma unroll
    for (int i = 0; i < 2; i++)
#pragma unroll
      for (int j = 0; j < 4; j++) acc[i][j] = (floatx4){0.f, 0.f, 0.f, 0.f};
    const bf16_t* arow = BmT + (long)bc * 128 * 256;
    const bf16_t* brow = xdT + (long)blk * 64 * 256;
    const float* acsb = acs + (long)blk * 256;
    const float at = ctot[blk];      // log2-scaled chunk total (<= acs[l])
#pragma unroll
    for (int kt = 0; kt < 8; kt++) {
      const int lbase = kt * 32 + l4 * 8;
      float e[8];
      *(float4*)&e[0] = *(const float4*)(acsb + lbase);
      *(float4*)&e[4] = *(const float4*)(acsb + lbase + 4);
#pragma unroll
      for (int q = 0; q < 8; q++) e[q] = exp2f(at - e[q]);
      bfrag8 af[2];
      fragu bfr[4];
#pragma unroll
      for (int i = 0; i < 2; i++)
        af[i] = *(const bfrag8*)(arow + (long)(wv * 32 + i * 16 + l15) * 256 + lbase);
#pragma unroll
      for (int j = 0; j < 4; j++) {
        uint4 u = *(const uint4*)(brow + (long)(j * 16 + l15) * 256 + lbase);
        float v[8];
        unp8(u, v);
#pragma unroll
        for (int q2 = 0; q2 < 4; q2++)
          bfr[j].u[q2] = pack_bf16_rn(v[q2 * 2] * e[q2 * 2], v[q2 * 2 + 1] * e[q2 * 2 + 1]);
      }
#pragma unroll
      for (int i = 0; i < 2; i++)
#pragma unroll
        for (int j = 0; j < 4; j++)
          acc[i][j] = __builtin_amdgcn_mfma_f32_16x16x32_bf16(af[i], bfr[j].f, acc[i][j], 0, 0, 0);
    }
#pragma unroll
    for (int i = 0; i < 2; i++)
#pragma unroll
      for (int j = 0; j < 4; j++) {
        int n_base = wv * 32 + i * 16 + l4 * 4;
        int p = j * 16 + l15;
        unsigned lo = pack_bf16_rn(acc[i][j][0], acc[i][j][1]);
        unsigned hi = pack_bf16_rn(acc[i][j][2], acc[i][j][3]);
        *(uint2*)(states + (long)blk * 8192 + p * 128 + n_base) = make_uint2(lo, hi);
      }
  } else {
    // ---- S GEMM: SL[bc][l][s] = Cm[l].Bm[s] (M=N=256 in 128-tiles, K=128) ----
    int idx = blockIdx.x - 512;         // 0..63
    const int bc = idx >> 2;
    const int tm = ((idx >> 1) & 1) << 7;
    const int tn = (idx & 1) << 7;
    const int wm = (wv >> 1) << 6;
    const int wn = (wv & 1) << 6;
    floatx4 acc[4][4];
#pragma unroll
    for (int i = 0; i < 4; i++)
#pragma unroll
      for (int j = 0; j < 4; j++) acc[i][j] = (floatx4){0.f, 0.f, 0.f, 0.f};
    const int arow = t >> 2;
    const int acol = (t & 3) << 3;
    const bf16_t* Ag = Cmh + (long)bc * 256 * DSTATE + (long)(tm + arow) * DSTATE + acol;
    const bf16_t* Bg = Bmh + (long)bc * 256 * DSTATE + (long)(tn + arow) * DSTATE + acol;
    const long k64 = (long)64 * DSTATE;
    for (int k0 = 0; k0 < DSTATE; k0 += 32) {
      gl_lds16(Ag + k0, &As[t * 8]);
      gl_lds16(Ag + k64 + k0, &As[2048 + t * 8]);
      gl_lds16(Bg + k0, &Bs[t * 8]);
      gl_lds16(Bg + k64 + k0, &Bs[2048 + t * 8]);
      __syncthreads();
      bfrag8 af[4], bfr[4];
#pragma unroll
      for (int i = 0; i < 4; i++)
        af[i] = *(const bfrag8*)&As[(wm + i * 16 + l15) * 32 + l4 * 8];
#pragma unroll
      for (int j = 0; j < 4; j++)
        bfr[j] = *(const bfrag8*)&Bs[(wn + j * 16 + l15) * 32 + l4 * 8];
#pragma unroll
      for (int i = 0; i < 4; i++)
#pragma unroll
        for (int j = 0; j < 4; j++)
          acc[i][j] = __builtin_amdgcn_mfma_f32_16x16x32_bf16(af[i], bfr[j], acc[i][j], 0, 0, 0);
      __syncthreads();
    }
    bf16_t* Cb = SL + (long)bc * 65536;
#pragma unroll
    for (int i = 0; i < 4; i++)
#pragma unroll
      for (int j = 0; j < 4; j++)
#pragma unroll
        for (int r = 0; r < 4; r++)
          Cb[(long)(tm + wm + i * 16 + l4 * 4 + r) * 256 + tn + wn + j * 16 + l15] =
              __float2bfloat16(acc[i][j][r]);
  }
}

// ---------------- vectorized conv4 + bias + silu: 8 channels x 4 rows / thread -------
__global__ __launch_bounds__(256) void conv4_kernel(const bf16_t* __restrict__ zxh,
    const float* __restrict__ cw, const float* __restrict__ cb,
    bf16_t* __restrict__ xhb, bf16_t* __restrict__ Bmh, bf16_t* __restrict__ Cmh) {
  int g = blockIdx.x * 256 + threadIdx.x;    // < 1024*288
  int cg = g % 288;
  int blt = g / 288;
  int c0 = cg * 8;
  long bl0 = (long)blt * 4;
  int l0 = (int)(bl0 & (LL - 1));
  const bf16_t* base = zxh + bl0 * NPAD + DI + c0;
  float rv[7][8];
#pragma unroll
  for (int j = 0; j < 7; j++) {
    int dj = j - 3;
    if (l0 + dj >= 0) {
      uint4 u = *(const uint4*)(base + (long)dj * NPAD);
      unp8(u, rv[j]);
    } else {
#pragma unroll
      for (int q = 0; q < 8; q++) rv[j][q] = 0.f;
    }
  }
  float4 wq[8];
#pragma unroll
  for (int q = 0; q < 8; q++) wq[q] = ((const float4*)cw)[c0 + q];
  float bias[8];
  *(float4*)&bias[0] = *(const float4*)(cb + c0);
  *(float4*)&bias[4] = *(const float4*)(cb + c0 + 4);
#pragma unroll
  for (int i = 0; i < 4; i++) {
    unsigned o[4];
#pragma unroll
    for (int q2 = 0; q2 < 4; q2++) {
      float rr[2];
#pragma unroll
      for (int e = 0; e < 2; e++) {
        int q = q2 * 2 + e;
        float a = bias[q] + wq[q].x * rv[i][q] + wq[q].y * rv[i + 1][q]
                + wq[q].z * rv[i + 2][q] + wq[q].w * rv[i + 3][q];
        rr[e] = a / (1.f + __expf(-a));
      }
      o[q2] = pack_bf16_rn(rr[0], rr[1]);
    }
    uint4 ov = make_uint4(o[0], o[1], o[2], o[3]);
    long bl = bl0 + i;
    if (c0 < DI)               *(uint4*)(xhb + bl * DI + c0) = ov;
    else if (c0 < DI + DSTATE) *(uint4*)(Bmh + bl * DSTATE + (c0 - DI)) = ov;
    else                       *(uint4*)(Cmh + bl * DSTATE + (c0 - DI - DSTATE)) = ov;
  }
}

// ------- fused: softplus(dt)+cumsum (per b,c,h) + transpose xdT; BmT branch ----------
// (xdTe eliminated — its decay scale is applied on the fly in sst's states path.)
__global__ __launch_bounds__(256) void xdt_kernel(const bf16_t* __restrict__ xhb,
    const bf16_t* __restrict__ Bmh, const bf16_t* __restrict__ zxh,
    const float* __restrict__ A_log, const float* __restrict__ dtb,
    float* __restrict__ acs, float* __restrict__ ctot,
    bf16_t* __restrict__ xdT, bf16_t* __restrict__ BmT) {
  __shared__ unsigned short Tb[9216];   // 64x72 (xdt) or 1x 128x72 (bmt)
  __shared__ float acsL[256];
  __shared__ float dtsL[256];
  __shared__ float wsum[4];
  int blk = blockIdx.x;
  int t = threadIdx.x;
  if (blk < 512) {
    int h = blk & 31, bc = blk >> 5;
    {   // ---- fused softplus + log2-scaled cumsum ----
      int lane = t & 63, w = t >> 6;
      float Ah = -__expf(A_log[h]) * LOG2E;
      int gl = bc * 256 + t;
      float vv = __bfloat162float(zxh[(long)gl * NPAD + (NPROJ - 32) + h]) + dtb[h];
      float sp = fmaxf(vv, 0.f) + log1pf(__expf(-fabsf(vv)));
      float a = sp * Ah;
#pragma unroll
      for (int off = 1; off < 64; off <<= 1) {
        float v = __shfl_up(a, off, 64);
        if (lane >= off) a += v;
      }
      if (lane == 63) wsum[w] = a;
      __syncthreads();
      float base = 0.f;
      for (int i = 0; i < 4; i++) base += (i < w) ? wsum[i] : 0.f;
      a += base;
      acsL[t] = a;
      dtsL[t] = sp;
      acs[blk * 256 + t] = a;
      if (t == 255) ctot[blk] = a;
      __syncthreads();
    }
    unsigned short* T1 = Tb;
    int l_loc = t >> 2, pg = t & 3;
    for (int lt = 0; lt < 4; lt++) {
      int ll = lt * 64 + l_loc;
      int gl = bc * 256 + ll;
      float w1 = dtsL[ll];
      const uint4* src = (const uint4*)(xhb + (long)gl * DI + h * HD + pg * 16);
      uint4 u0 = src[0], u1 = src[1];
      float v[16];
      unp8(u0, v); unp8(u1, v + 8);
      __syncthreads();
#pragma unroll
      for (int q = 0; q < 16; q++)
        T1[(pg * 16 + q) * 72 + l_loc] = bf16u(v[q] * w1);
      __syncthreads();
      long orow = ((long)blk * 64 + l_loc) * 256 + lt * 64 + pg * 16;
      *(uint4*)(xdT + orow)     = *(uint4*)&T1[l_loc * 72 + pg * 16];
      *(uint4*)(xdT + orow + 8) = *(uint4*)&T1[l_loc * 72 + pg * 16 + 8];
    }
  } else {
    unsigned short* T = Tb;
    int bc = blk - 512;
    int l_loc = t >> 2, ng = t & 3;
    for (int lt = 0; lt < 4; lt++) {
      int gl = bc * 256 + lt * 64 + l_loc;
      const uint4* src = (const uint4*)(Bmh + (long)gl * DSTATE + ng * 32);
      uint4 u[4];
#pragma unroll
      for (int q = 0; q < 4; q++) u[q] = src[q];
      __syncthreads();
      const unsigned short* us = (const unsigned short*)u;
#pragma unroll
      for (int e = 0; e < 32; e++)
        T[(ng * 32 + e) * 72 + l_loc] = us[e];
      __syncthreads();
      int n = t >> 1, lg2 = t & 1;
      long orow = ((long)bc * 128 + n) * 256 + lt * 64 + lg2 * 32;
#pragma unroll
      for (int q = 0; q < 4; q++)
        *(uint4*)(BmT + orow + q * 8) = *(uint4*)&T[n * 72 + lg2 * 32 + q * 8];
    }
  }
}

// ---------------- inter-chunk scan -> init states (bf16 in/out; ctot log2-scaled) -----
__global__ void scan_kernel(const bf16_t* __restrict__ states, const float* __restrict__ ctot,
                            bf16_t* __restrict__ initsb) {
  int id = blockIdx.x * 256 + threadIdx.x;   // < 2*32*8192
  int pn = id & 8191;
  int bh = id >> 13;
  int b = bh >> 5, h = bh & 31;
  float S = 0.f;
#pragma unroll
  for (int c = 0; c < 8; c++) {
    int blk = (b * 8 + c) * 32 + h;
    initsb[(long)blk * 8192 + pn] = __float2bfloat16(S);
    S = exp2f(ctot[blk]) * S + __bfloat162float(states[(long)blk * 8192 + pn]);
  }
}

// ------- MFMA Y: register A-frags (P computed in-layout), no per-tile barriers -------
// 512 threads: waves 0-3 rows 0-127 (mh=0), waves 4-7 rows 128-255 (mh=1).
// SL is bf16 (halves the ~100MB L2/LLC SL stream; values were bf16-packed anyway).
__global__ __launch_bounds__(512, 4) void yk4_kernel(const bf16_t* __restrict__ SL,
     const bf16_t* __restrict__ Cmh, const bf16_t* __restrict__ xhb,
     const bf16_t* __restrict__ zxh, const float* __restrict__ acs,
     const bf16_t* __restrict__ initsb, const bf16_t* __restrict__ xdT,
     const float* __restrict__ Dp, bf16_t* __restrict__ yg, float* __restrict__ ssqp) {
  int bi = blockIdx.x;                       // XCD-swizzled mapping
  int bc = (bi & 7) * 2 + ((bi >> 3) & 1);
  int h = bi >> 4;
  int ablk = bc * 32 + h;
  int t = threadIdx.x;
  int wv = t >> 6;
  int mh = wv >> 2, wsub = wv & 3;
  int lane = t & 63;
  int l15 = lane & 15, l4 = lane >> 4;

  __shared__ float acsS[256];
  __shared__ __align__(16) char bbuf[49152];   // union: {xds 32KB + ins 16KB} / Yt 33.8KB
  bf16_t* xds = (bf16_t*)bbuf;                 // [64][256] swizzled
  bf16_t* ins = (bf16_t*)(bbuf + 32768);       // [64][128] swizzled
  float* Yt = (float*)bbuf;                    // [128][66]

  {
    const bf16_t* xrow_g = xdT + (long)ablk * 64 * 256;
#pragma unroll
    for (int it = 0; it < 4; it++) {
      int sl = it * 512 + t;
      int p = sl >> 5, s = sl & 31;
      int c = (s & 24) | ((s & 7) ^ (p & 7));
      gl_lds16(xrow_g + p * 256 + c * 8, &xds[sl * 8]);
    }
    const bf16_t* irow_g = initsb + (long)ablk * 8192;
#pragma unroll
    for (int it = 0; it < 2; it++) {
      int sl = it * 512 + t;
      int p = sl >> 4, s = sl & 15;
      int c = (s & 8) | ((s & 7) ^ (p & 7));
      gl_lds16(irow_g + p * 128 + c * 8, &ins[sl * 8]);
    }
  }
  if (t < 256) acsS[t] = acs[ablk * 256 + t];
  __syncthreads();

  const int rowbase = bc * 256;
  const int l0 = mh * 128 + wsub * 32 + l15;
  const int l1 = l0 + 16;
  const float al0 = acsS[l0], al1 = acsS[l1];
  const float eA0 = exp2f(al0), eA1 = exp2f(al1);
  const bf16_t* SL0 = SL + (long)bc * 65536 + (long)l0 * 256;
  const bf16_t* SL1 = SL + (long)bc * 65536 + (long)l1 * 256;

  floatx4 acc[2][4];
#pragma unroll
  for (int i = 0; i < 2; i++)
#pragma unroll
    for (int j = 0; j < 4; j++) acc[i][j] = (floatx4){0.f, 0.f, 0.f, 0.f};

  const int nkd = (mh + 1) * 4;
  for (int kt = 0; kt < nkd; kt++) {           // diagonal tiles, no barriers
    int sbase = kt * 32 + l4 * 8;
    float as[8];
    *(float4*)&as[0] = *(const float4*)&acsS[sbase];
    *(float4*)&as[4] = *(const float4*)&acsS[sbase + 4];
    float sv0[8], sv1[8];
    unp8(*(const uint4*)(SL0 + sbase), sv0);
    unp8(*(const uint4*)(SL1 + sbase), sv1);
    fragu af0, af1;
#pragma unroll
    for (int q2 = 0; q2 < 4; q2++) {
      float p00, p01, p10, p11;
      {
        int s = sbase + q2 * 2;
        float d0 = al0 - as[q2 * 2], d1 = al0 - as[q2 * 2 + 1];
        p00 = (s <= l0) ? sv0[q2 * 2] * exp2f(fminf(d0, 0.f)) : 0.f;
        p01 = (s + 1 <= l0) ? sv0[q2 * 2 + 1] * exp2f(fminf(d1, 0.f)) : 0.f;
        float e0 = al1 - as[q2 * 2], e1 = al1 - as[q2 * 2 + 1];
        p10 = (s <= l1) ? sv1[q2 * 2] * exp2f(fminf(e0, 0.f)) : 0.f;
        p11 = (s + 1 <= l1) ? sv1[q2 * 2 + 1] * exp2f(fminf(e1, 0.f)) : 0.f;
      }
      af0.u[q2] = pack_bf16_rn(p00, p01);
      af1.u[q2] = pack_bf16_rn(p10, p11);
    }
    bfrag8 bfr[4];
    int ch = kt * 4 + l4;
#pragma unroll
    for (int j = 0; j < 4; j++) {
      int p = j * 16 + l15;
      int sw = (ch & 24) | ((ch & 7) ^ (p & 7));
      bfr[j] = *(const bfrag8*)&xds[(p * 32 + sw) * 8];
    }
#pragma unroll
    for (int j = 0; j < 4; j++) {
      acc[0][j] = __builtin_amdgcn_mfma_f32_16x16x32_bf16(af0.f, bfr[j], acc[0][j], 0, 0, 0);
      acc[1][j] = __builtin_amdgcn_mfma_f32_16x16x32_bf16(af1.f, bfr[j], acc[1][j], 0, 0, 0);
    }
  }
#pragma unroll
  for (int kt = 0; kt < 4; kt++) {             // off-diagonal (Y_off) tiles
    int n0 = kt * 32 + l4 * 8;
    uint4 c0 = *(const uint4*)(Cmh + (long)(rowbase + l0) * DSTATE + n0);
    uint4 c1 = *(const uint4*)(Cmh + (long)(rowbase + l1) * DSTATE + n0);
    float cv0[8], cv1[8];
    unp8(c0, cv0); unp8(c1, cv1);
    fragu af0, af1;
#pragma unroll
    for (int q2 = 0; q2 < 4; q2++) {
      af0.u[q2] = pack_bf16_rn(cv0[q2 * 2] * eA0, cv0[q2 * 2 + 1] * eA0);
      af1.u[q2] = pack_bf16_rn(cv1[q2 * 2] * eA1, cv1[q2 * 2 + 1] * eA1);
    }
    bfrag8 bfr[4];
    int ch = kt * 4 + l4;
#pragma unroll
    for (int j = 0; j < 4; j++) {
      int p = j * 16 + l15;
      int sw = (ch & 8) | ((ch & 7) ^ (p & 7));
      bfr[j] = *(const bfrag8*)&ins[(p * 16 + sw) * 8];
    }
#pragma unroll
    for (int j = 0; j < 4; j++) {
      acc[0][j] = __builtin_amdgcn_mfma_f32_16x16x32_bf16(af0.f, bfr[j], acc[0][j], 0, 0, 0);
      acc[1][j] = __builtin_amdgcn_mfma_f32_16x16x32_bf16(af1.f, bfr[j], acc[1][j], 0, 0, 0);
    }
  }
  // ---- two-pass epilogue through Yt (union over xds/ins) ----
  float Dh = Dp[h];
#pragma unroll
  for (int pass = 0; pass < 2; pass++) {
    __syncthreads();
    if (mh == pass) {
#pragma unroll
      for (int i = 0; i < 2; i++)
#pragma unroll
        for (int j = 0; j < 4; j++)
#pragma unroll
          for (int r = 0; r < 4; r++)
            Yt[(wsub * 32 + i * 16 + l4 * 4 + r) * 66 + j * 16 + l15] = acc[i][j][r];
    }
    __syncthreads();
    {
      int row_l = t >> 2;
      int chc = (t & 3) * 16;
      long rowg = rowbase + pass * 128 + row_l;
      float ss = 0.f;
#pragma unroll
      for (int it = 0; it < 2; it++) {
        int c = chc + it * 8;
        float4 y0 = *(const float4*)&Yt[row_l * 66 + c];
        float4 y1 = *(const float4*)&Yt[row_l * 66 + c + 4];
        uint4 ux = *(const uint4*)(xhb + rowg * DI + h * HD + c);
        uint4 uz = *(const uint4*)(zxh + rowg * NPAD + h * HD + c);
        float xv[8], zv[8];
        unp8(ux, xv); unp8(uz, zv);
        float yv[8] = {y0.x, y0.y, y0.z, y0.w, y1.x, y1.y, y1.z, y1.w};
        unsigned o[4];
#pragma unroll
        for (int q = 0; q < 4; q++) {
          float v0 = (yv[q * 2 + 0] + Dh * xv[q * 2 + 0]) *
                     (zv[q * 2 + 0] / (1.f + __expf(-zv[q * 2 + 0])));
          float v1 = (yv[q * 2 + 1] + Dh * xv[q * 2 + 1]) *
                     (zv[q * 2 + 1] / (1.f + __expf(-zv[q * 2 + 1])));
          ss += v0 * v0 + v1 * v1;
          o[q] = pack_bf16_rn(v0, v1);
        }
        *(uint4*)(yg + rowg * DI + h * HD + c) = make_uint4(o[0], o[1], o[2], o[3]);
      }
      ss += __shfl_xor(ss, 1, 64);
      ss += __shfl_xor(ss, 2, 64);
      if ((t & 3) == 0) ssqp[rowg * 32 + h] = ss;
    }
  }
}

extern "C" void kernel_launch(void* const* d_in, const int* in_sizes, int n_in,
                              void* d_out, int out_size, void* d_ws, size_t ws_size,
                              hipStream_t stream) {
  const float* x    = (const float*)d_in[0];
  const float* nw   = (const float*)d_in[1];
  const float* w1   = (const float*)d_in[2];
  const float* cw   = (const float*)d_in[3];
  const float* cb   = (const float*)d_in[4];
  const float* dtb  = (const float*)d_in[5];
  const float* alog = (const float*)d_in[6];
  const float* Dp   = (const float*)d_in[7];
  const float* gw   = (const float*)d_in[8];
  const float* w2   = (const float*)d_in[9];
  float* out = (float*)d_out;

  char* ws = (char*)d_ws;
  size_t off = 0;
  auto alloc = [&](size_t bytes) -> void* {
    void* p = ws + off;
    off += (bytes + 255) & ~(size_t)255;
    return p;
  };
  bf16_t* ub     = (bf16_t*)alloc((size_t)MR * DM * 2);
  bf16_t* w1b    = (bf16_t*)alloc((size_t)NPAD * DM * 2);
  bf16_t* w2b    = (bf16_t*)alloc((size_t)DM * DI * 2);
  bf16_t* zxh    = (bf16_t*)alloc((size_t)MR * NPAD * 2);
  bf16_t* xhb    = (bf16_t*)alloc((size_t)MR * DI * 2);
  bf16_t* Bmh    = (bf16_t*)alloc((size_t)MR * DSTATE * 2);
  bf16_t* Cmh    = (bf16_t*)alloc((size_t)MR * DSTATE * 2);
  bf16_t* SL     = (bf16_t*)alloc((size_t)16 * 256 * 256 * 2);
  float* acs     = (float*)alloc((size_t)512 * 256 * 4);
  float* ctot    = (float*)alloc((size_t)512 * 4);
  bf16_t* states = (bf16_t*)alloc((size_t)512 * 8192 * 2);
  bf16_t* initsb = (bf16_t*)alloc((size_t)512 * 8192 * 2);
  bf16_t* xdT    = (bf16_t*)alloc((size_t)512 * 64 * 256 * 2);
  bf16_t* BmT    = (bf16_t*)alloc((size_t)16 * 128 * 256 * 2);
  bf16_t* yg     = (bf16_t*)alloc((size_t)MR * DI * 2);
  float* ssqp    = (float*)alloc((size_t)MR * NHD * 4);
  if (off > ws_size) return;

  rms_cvt_kernel<<<MR + CVTBLK, 256, 0, stream>>>(x, nw, ub, w1, w2, gw, w1b, w2b);
  // in_proj: single launch — 256 main (8-phase 256^2, cols [0,4096)) + 160 K-split
  // remainder blocks (cols [4096,4416); >=4416 is never-read pad).
  gemm256_kernel<<<416, 512, 0, stream>>>(ub, w1b, zxh);
  conv4_kernel<<<(1024 * 288) / 256, 256, 0, stream>>>(zxh, cw, cb, xhb, Bmh, Cmh);
  xdt_kernel<<<528, 256, 0, stream>>>(xhb, Bmh, zxh, alog, dtb, acs, ctot, xdT, BmT);
  sst_kernel<<<576, 256, 0, stream>>>(xdT, BmT, states, Cmh, Bmh, SL, acs, ctot);
  scan_kernel<<<(2 * 32 * 8192) / 256, 256, 0, stream>>>(states, ctot, initsb);
  yk4_kernel<<<512, 512, 0, stream>>>(SL, Cmh, xhb, zxh, acs, initsb, xdT, Dp, yg, ssqp);
  // out_proj: TN=64 grid 32x16 (512 blocks = 2/CU) + XCD swizzle + fused rms reduction
  gemm64_kernel<64, true, false><<<dim3(MR / 128, DM / 64), 256, 0, stream>>>(
      yg, w2b, x, ssqp, out, DM, DI);
}